// Round 1
// 745.592 us; speedup vs baseline: 1.0877x; 1.0877x over previous
//
#include <hip/hip_runtime.h>

#define NN 8192      // nodes
#define SS 20        // seq len
#define DD 256       // feat dim = H
#define RGATE 1024   // 4H
#define KKD 512      // D + H

typedef __attribute__((ext_vector_type(8))) short short8;
typedef __attribute__((ext_vector_type(4))) float f32x4;

__device__ __forceinline__ unsigned short f2bf(float f) {
    unsigned int u = __float_as_uint(f);
    u += 0x7FFFu + ((u >> 16) & 1u);   // round-to-nearest-even
    return (unsigned short)(u >> 16);
}

__device__ __forceinline__ void async_copy16(const void* g, void* l) {
    __builtin_amdgcn_global_load_lds(
        (const __attribute__((address_space(1))) void*)g,
        (__attribute__((address_space(3))) void*)l, 16, 0, 0);
}

__device__ __forceinline__ float sigm(float x) { return 1.0f / (1.0f + __expf(-x)); }
__device__ __forceinline__ float tanh_(float x) { return 2.0f / (1.0f + __expf(-2.0f * x)) - 1.0f; }

// ---------------------------------------------------------------------------
// Weight repack: Wcat[dir][r'][k], r' = 4*j + gate; k<256 -> w_ih, else w_hh.
// ---------------------------------------------------------------------------
__global__ void convert_w(const float* __restrict__ wihf, const float* __restrict__ whhf,
                          const float* __restrict__ bf,   const float* __restrict__ wihb,
                          const float* __restrict__ whhb, const float* __restrict__ bb,
                          unsigned short* __restrict__ Wcat, float* __restrict__ bperm) {
    const int idx = blockIdx.x * 256 + threadIdx.x;   // < 2*1024*512
    const int dir = idx >> 19;
    const int rem = idx & ((1 << 19) - 1);
    const int rp  = rem >> 9;          // r' in [0,1024)
    const int k   = rem & 511;
    const int j   = rp >> 2, gi = rp & 3;
    const int r   = gi * 256 + j;      // original row (PyTorch i,f,g,o blocks)
    const float* wih = dir ? wihb : wihf;
    const float* whh = dir ? whhb : whhf;
    const float v = (k < 256) ? wih[r * 256 + k] : whh[r * 256 + (k - 256)];
    Wcat[idx] = f2bf(v);
    if (k == 0) {
        const float* b = dir ? bb : bf;
        bperm[dir * 1024 + rp] = b[r];
    }
}

// ---------------------------------------------------------------------------
// Gather neighbor embeddings to bf16: X[t][n][256]. 4 waves/block, 1 row/wave.
// ---------------------------------------------------------------------------
__global__ __launch_bounds__(256) void gather_x(const float* __restrict__ emb,
                                                const int* __restrict__ idx,
                                                unsigned short* __restrict__ X) {
    const int w = threadIdx.x >> 6, lane = threadIdx.x & 63;
    #pragma unroll 4
    for (int i = 0; i < 16; ++i) {
        const int rid = (blockIdx.x * 16 + i) * 4 + w;   // 0..163839 = n*SS+t
        const int n = rid / SS, t = rid - n * SS;
        const int row = idx[rid];
        const float4 v = ((const float4*)(emb + (size_t)row * DD))[lane];
        ushort4 o;
        o.x = f2bf(v.x); o.y = f2bf(v.y); o.z = f2bf(v.z); o.w = f2bf(v.w);
        ((ushort4*)(X + ((size_t)t * NN + n) * DD))[lane] = o;
    }
}

// ---------------------------------------------------------------------------
// One LSTM step, both dirs. Grid 256 (1 block/CU), 512 thr (8 waves).
// Block tile 256 rows x 256 gate cols; wave tile 64x128: acc[4][8].
// BK=32, 16 rounds.
// K-loop restructured this round (T4, counted vmcnt): 3-deep LDS pipeline,
// stage(r+2) issued at END of round r (all round r-1 readers of that buffer
// have provably passed this round's barrier), waited ~2 rounds later with
// s_waitcnt vmcnt(4). No vmcnt(0) drain in the main loop (the old
// __syncthreads drained the same-round prefetch -> <1 round of latency
// cover; m233-regime stall). Same barrier count as before (1/round).
// LDS 64-B rows (4x16B segs), seg' = quad ^ ((row>>1)&3): 2-way = free.
// h/c in global, XCD-L2-resident via decode: xcd=b&7, dir=b&1 (W per parity),
// mslab tied to XCD-pair so A panels shared by the 4 nblk blocks on-XCD.
// ---------------------------------------------------------------------------
__global__ __launch_bounds__(512, 2) void lstm_step(
    const unsigned short* __restrict__ X,      // [SS][NN][256] bf16
    const unsigned short* __restrict__ Wcat,   // [2][1024][512] bf16
    const float* __restrict__ bperm,           // [2][1024]
    unsigned short* __restrict__ hping,        // [2 ping][2 dir][NN][256] bf16
    float* __restrict__ cstate,                // [2 dir][NN][256] f32
    float* __restrict__ hsum,                  // [NN] f32
    int s) {
    const int b     = blockIdx.x;              // 0..255
    const int dir   = b & 1;
    const int nblk  = (b >> 3) & 3;            // 0..3 (256 gate cols each)
    const int mslab = (((b & 7) >> 1) << 3) | (b >> 5);   // 0..31
    const int m0    = mslab * 256;
    const int n0    = nblk * 256;

    const int t = dir ? (SS - 1 - s) : s;
    const unsigned short* Xt    = X + (size_t)t * NN * DD;
    const unsigned short* hprev = hping + ((size_t)((s & 1) * 2 + dir)) * NN * 256;
    unsigned short*       hnext = hping + ((size_t)((((s + 1) & 1) * 2) + dir)) * NN * 256;
    const unsigned short* W     = Wcat + (size_t)dir * RGATE * KKD;
    const float*          bp    = bperm + dir * RGATE;
    float*                cdir  = cstate + (size_t)dir * NN * 256;

    __shared__ __align__(16) char smem[98304];
    // A bufs: [0,48K) = 3 x 16K;  B bufs: [48K,96K) = 3 x 16K
    // epilogue scratch (34.8 KB) overlays [0, ...) after the K-loop.

    const int tid  = threadIdx.x;
    const int lane = tid & 63;
    const int w    = tid >> 6;        // 0..7
    const int wm   = w >> 1, wn = w & 1;
    const int quad = lane >> 4, l15 = lane & 15;
    const int jq   = lane & 3,  rl  = lane >> 2;

    // staging lane constants: lane covers LDS (row=base+(lane>>2), seg=lane&3)
    // which must hold global seg (lane&3) ^ ((row>>1)&3) = (lane&3)^((lane>>3)&3)
    const int srow  = lane >> 2;
    const int gsegl = (lane & 3) ^ ((lane >> 3) & 3);

    auto stage = [&](int rr, int buf) {
        const int k0 = (rr & 7) * 32;                      // col within X or h
        const unsigned short* Asrc = (rr < 8) ? Xt : hprev;
        char* Ad = smem + buf * 16384;
        char* Bd = smem + 49152 + buf * 16384;
        #pragma unroll
        for (int i = 0; i < 2; ++i) {
            const int lr = w * 32 + i * 16 + srow;         // local row 0..255
            async_copy16(Asrc + (size_t)(m0 + lr) * DD + k0 + gsegl * 8,
                         (void*)(Ad + (w * 32 + i * 16) * 64));
            async_copy16(W + (size_t)(n0 + lr) * KKD + rr * 32 + gsegl * 8,
                         (void*)(Bd + (w * 32 + i * 16) * 64));
        }
    };

    f32x4 acc[4][8];
    #pragma unroll
    for (int i = 0; i < 4; ++i)
        #pragma unroll
        for (int j = 0; j < 8; ++j) acc[i][j] = f32x4{0.f, 0.f, 0.f, 0.f};

    const int sA = (quad ^ ((l15 >> 1) & 3)) * 16;   // frag-read seg byte offset

    auto krnd = [&](int cb) {
        const char* Ab = smem + cb * 16384;
        const char* Bb = smem + 49152 + cb * 16384;
        short8 af[4], bfr[8];
        #pragma unroll
        for (int mt = 0; mt < 4; ++mt)
            af[mt] = *(const short8*)(Ab + (wm * 64 + mt * 16 + l15) * 64 + sA);
        #pragma unroll
        for (int nt = 0; nt < 8; ++nt)
            bfr[nt] = *(const short8*)(Bb + (wn * 128 + nt * 16 + l15) * 64 + sA);
        #pragma unroll
        for (int mt = 0; mt < 4; ++mt)
            #pragma unroll
            for (int nt = 0; nt < 8; ++nt)
                acc[mt][nt] = __builtin_amdgcn_mfma_f32_16x16x32_bf16(
                    af[mt], bfr[nt], acc[mt][nt], 0, 0, 0);
    };

    // ---- K-loop: 3-buffer pipeline, counted vmcnt, no main-loop drain ----
    stage(0, 0);
    stage(1, 1);
    {
        int cb = 0, sb = 2;
        #pragma unroll
        for (int r = 0; r < 14; ++r) {
            asm volatile("s_waitcnt vmcnt(4)" ::: "memory");  // stage(r) landed (mine)
            asm volatile("s_barrier" ::: "memory");           // ... and everyone's
            krnd(cb);
            stage(r + 2, sb);   // -> buf (r-1)%3; its readers passed the barrier above
            cb = (cb == 2) ? 0 : cb + 1;
            sb = (sb == 2) ? 0 : sb + 1;
        }
        asm volatile("s_waitcnt vmcnt(4)" ::: "memory");      // stage(14) landed
        asm volatile("s_barrier" ::: "memory");
        krnd(2);                                              // r = 14
        asm volatile("s_waitcnt vmcnt(0)" ::: "memory");      // stage(15) landed
        asm volatile("s_barrier" ::: "memory");
        krnd(0);                                              // r = 15
        asm volatile("s_barrier" ::: "memory");               // epilogue overlays bufs
    }

    // ---- epilogue: regroup gates (C/D -> unit-quads) via wave-private LDS ----
    float* my = (float*)smem + w * 1088;   // 16 x 68 floats per wave (34.8 KB)
    float hs[4] = {0.f, 0.f, 0.f, 0.f};

    #pragma unroll
    for (int half = 0; half < 2; ++half) {
        const int j0 = nblk * 64 + wn * 32 + half * 16 + jq * 4;  // global unit
        f32x4 bias4[4];
        #pragma unroll
        for (int jj = 0; jj < 4; ++jj)
            bias4[jj] = *(const f32x4*)(bp + 4 * (j0 + jj));
        #pragma unroll
        for (int mt = 0; mt < 4; ++mt) {
            #pragma unroll
            for (int nt = 0; nt < 4; ++nt) {
                const int ntg = half * 4 + nt;
                #pragma unroll
                for (int v = 0; v < 4; ++v)
                    my[(quad * 4 + v) * 68 + nt * 16 + l15] = acc[mt][ntg][v];
            }
            asm volatile("s_waitcnt lgkmcnt(0)" ::: "memory");
            const int mg = m0 + wm * 64 + mt * 16 + rl;
            float* cptr = cdir + (size_t)mg * 256 + j0;
            f32x4 cold = *(const f32x4*)cptr;
            f32x4 cnew;
            ushort4 hp;
            float lsum = 0.f;
            #pragma unroll
            for (int jj = 0; jj < 4; ++jj) {
                f32x4 g  = *(const f32x4*)(my + rl * 68 + (jq * 4 + jj) * 4);
                f32x4 bb = bias4[jj];
                const float gi = sigm(g.x + bb.x);   // i
                const float gf = sigm(g.y + bb.y);   // f
                const float gg = tanh_(g.z + bb.z);  // g
                const float go = sigm(g.w + bb.w);   // o
                const float cn = gf * cold[jj] + gi * gg;
                cnew[jj] = cn;
                const float hv = go * tanh_(cn);
                lsum += hv;
                ((unsigned short*)&hp)[jj] = f2bf(hv);
            }
            *(f32x4*)cptr = cnew;
            *(ushort4*)(hnext + (size_t)mg * 256 + j0) = hp;
            hs[mt] += lsum;
        }
    }

    // per-row partial sums -> one atomic per (wave, row)
    #pragma unroll
    for (int mt = 0; mt < 4; ++mt) {
        float v = hs[mt];
        v += __shfl_xor(v, 1);
        v += __shfl_xor(v, 2);
        if (jq == 0) atomicAdd(&hsum[m0 + wm * 64 + mt * 16 + rl], v);
    }
}

__global__ void bcast_out(const float* __restrict__ hsum, float* __restrict__ out) {
    const int n = blockIdx.x;
    const float v = hsum[n] * (1.0f / 512.0f);
    float2 p; p.x = v; p.y = v;
    ((float2*)(out + (size_t)n * 512))[threadIdx.x] = p;
}

extern "C" void kernel_launch(void* const* d_in, const int* in_sizes, int n_in,
                              void* d_out, int out_size, void* d_ws, size_t ws_size,
                              hipStream_t stream) {
    const float* emb  = (const float*)d_in[0];
    const float* wihf = (const float*)d_in[1];
    const float* whhf = (const float*)d_in[2];
    const float* bf   = (const float*)d_in[3];
    const float* wihb = (const float*)d_in[4];
    const float* whhb = (const float*)d_in[5];
    const float* bb   = (const float*)d_in[6];
    const int*   idx  = (const int*)d_in[7];
    float* out = (float*)d_out;

    // workspace layout (bytes)
    char* ws = (char*)d_ws;
    unsigned short* X     = (unsigned short*)(ws);               // 83,886,080  X[t][n][256] bf16
    unsigned short* Wcat  = (unsigned short*)(ws + 83886080);    //  2,097,152  [2][1024][512] bf16
    float*          bperm = (float*)(ws + 85983232);             //      8,192  [2][1024] f32
    unsigned short* hping = (unsigned short*)(ws + 85991424);    // 16,777,216  [2][2][8192][256] bf16
    float*          cst   = (float*)(ws + 102768640);            // 16,777,216  [2][8192][256] f32
    float*          hsum  = (float*)(ws + 119545856);            //     32,768  [8192] f32
    // total: 119,578,624 B

    hipMemsetAsync(hping, 0, 8388608, stream);                   // h ping0, both dirs
    hipMemsetAsync(cst, 0, 16777216 + 32768, stream);            // c + hsum (contiguous)

    convert_w<<<4096, 256, 0, stream>>>(wihf, whhf, bf, wihb, whhb, bb, Wcat, bperm);
    gather_x<<<2560, 256, 0, stream>>>(emb, idx, X);
    for (int s = 0; s < SS; ++s)
        lstm_step<<<256, 512, 0, stream>>>(X, Wcat, bperm, hping, cst, hsum, s);
    bcast_out<<<NN, 256, 0, stream>>>(hsum, out);
}